// Round 1
// baseline (142.755 us; speedup 1.0000x reference)
//
#include <hip/hip_runtime.h>

#define N_DOWN  50000
#define N_ABOVE 100000
#define DIM     256
#define FAN     5
#define K1      1280      // FAN * DIM
#define MPAD    100096    // 782 * 128

typedef __bf16 bf16x8 __attribute__((ext_vector_type(8)));
typedef float  f32x4  __attribute__((ext_vector_type(4)));

__device__ __forceinline__ unsigned short f2bf(float f) {
  unsigned u = __builtin_bit_cast(unsigned, f);
  u += 0x7FFFu + ((u >> 16) & 1u);          // RNE round to bf16
  return (unsigned short)(u >> 16);
}

__device__ __forceinline__ void gload16(const unsigned short* g, unsigned short* l) {
  __builtin_amdgcn_global_load_lds(
      (const __attribute__((address_space(1))) void*)g,
      (__attribute__((address_space(3))) void*)l, 16, 0, 0);
}

// ---- prep ----
__global__ void k_prep_inv(int* __restrict__ inv, unsigned short* __restrict__ hbf) {
  int t = blockIdx.x * 256 + threadIdx.x;
  if (t < N_ABOVE) inv[t] = N_DOWN;                 // sentinel -> zero row
  if (t < DIM)     hbf[(size_t)N_DOWN * DIM + t] = 0;
}

__global__ void k_scatter(const int* __restrict__ idx, int* __restrict__ inv) {
  int t = blockIdx.x * 256 + threadIdx.x;
  if (t < N_DOWN) inv[idx[t]] = t;
}

__global__ void k_h2bf(const float* __restrict__ h, unsigned short* __restrict__ hbf) {
  int t = blockIdx.x * 256 + threadIdx.x;           // grid sized exactly: 12500*256
  float4 v = ((const float4*)h)[t];
  ushort4 o;
  o.x = f2bf(v.x); o.y = f2bf(v.y); o.z = f2bf(v.z); o.w = f2bf(v.w);
  ((ushort4*)hbf)[t] = o;
}

// in: [K][N] f32 row-major -> out: [N][K] bf16 row-major
__global__ void k_transpose_bf(const float* __restrict__ in, unsigned short* __restrict__ out,
                               int K, int N) {
  __shared__ float tile[64][65];
  int k0 = blockIdx.x * 64, n0 = blockIdx.y * 64;
  int c = threadIdx.x & 63, rb = threadIdx.x >> 6;
#pragma unroll
  for (int rr = 0; rr < 16; ++rr) {
    int row = rb + rr * 4;
    tile[row][c] = in[(size_t)(k0 + row) * N + n0 + c];
  }
  __syncthreads();
#pragma unroll
  for (int rr = 0; rr < 16; ++rr) {
    int nr = rb + rr * 4;
    out[(size_t)(n0 + nr) * K + k0 + c] = f2bf(tile[c][nr]);
  }
}

// ---- GEMM1: hid = relu(gather(hbf) @ W1 + b1), bf16 out [MPAD][256] ----
__global__ __launch_bounds__(256, 2) void k_gemm1(
    const unsigned short* __restrict__ hbf,   // [N_DOWN+1][256] bf16
    const unsigned short* __restrict__ w1t,   // [256][1280]  bf16 (W1 transposed)
    const float* __restrict__ b1,
    const int* __restrict__ inv,              // [N_ABOVE]
    const int* __restrict__ jarr,             // [N_ABOVE*FAN]
    unsigned short* __restrict__ hid)         // [MPAD][256] bf16
{
  __shared__ __align__(16) unsigned short Alds[128 * 64];
  __shared__ __align__(16) unsigned short Blds[128 * 64];
  __shared__ int srcrow[128 * FAN];

  const int tid = threadIdx.x;
  const int w = tid >> 6, l = tid & 63;
  const int m0 = blockIdx.x * 128, n0 = blockIdx.y * 128;
  const int wm = w >> 1, wn = w & 1;
  const int srow = l >> 3, slot = l & 7;

  // per-block gather table: srcrow[row][r] = row of hbf feeding segment r
  for (int e = tid; e < 128 * FAN; e += 256) {
    int row = e / FAN, rr = e - row * FAN;
    int gm = m0 + row;
    int s = N_DOWN;
    if (gm < N_ABOVE) s = inv[jarr[(size_t)gm * FAN + rr]];
    srcrow[e] = s;
  }

  f32x4 acc[4][4] = {};

  for (int t = 0; t < 20; ++t) {
    const int r = t >> 2;                      // fan-in segment
    __syncthreads();                           // prev compute done; srcrow visible (t=0)
    // stage A (gathered rows), swizzled global source -> linear LDS dest
#pragma unroll
    for (int i = 0; i < 4; ++i) {
      int row = w * 32 + i * 8 + srow;
      int src = srcrow[row * FAN + r];
      int c = slot ^ (row & 7);
      gload16(hbf + ((size_t)src << 8) + ((t & 3) << 6) + (c << 3),
              Alds + (w * 32 + i * 8) * 64);
    }
    // stage B = W1T rows (n-major, contiguous k)
#pragma unroll
    for (int i = 0; i < 4; ++i) {
      int row = w * 32 + i * 8 + srow;
      int c = slot ^ (row & 7);
      gload16(w1t + (size_t)(n0 + row) * K1 + (t << 6) + (c << 3),
              Blds + (w * 32 + i * 8) * 64);
    }
    __syncthreads();                           // vmcnt drained by compiler before barrier

#pragma unroll
    for (int kk = 0; kk < 2; ++kk) {
      bf16x8 af[4], bfr[4];
#pragma unroll
      for (int m = 0; m < 4; ++m) {
        int row = wm * 64 + m * 16 + (l & 15);
        int c = (kk * 4 + (l >> 4)) ^ (row & 7);
        af[m] = *(const bf16x8*)(Alds + row * 64 + c * 8);
      }
#pragma unroll
      for (int n = 0; n < 4; ++n) {
        int row = wn * 64 + n * 16 + (l & 15);
        int c = (kk * 4 + (l >> 4)) ^ (row & 7);
        bfr[n] = *(const bf16x8*)(Blds + row * 64 + c * 8);
      }
#pragma unroll
      for (int m = 0; m < 4; ++m)
#pragma unroll
        for (int n = 0; n < 4; ++n)
          acc[m][n] = __builtin_amdgcn_mfma_f32_16x16x32_bf16(af[m], bfr[n], acc[m][n], 0, 0, 0);
    }
  }

  // epilogue: bias + relu -> bf16
#pragma unroll
  for (int n = 0; n < 4; ++n) {
    int gn = n0 + wn * 64 + n * 16 + (l & 15);
    float bias = b1[gn];
#pragma unroll
    for (int m = 0; m < 4; ++m) {
      int gm0 = m0 + wm * 64 + m * 16 + (l >> 4) * 4;
#pragma unroll
      for (int q = 0; q < 4; ++q) {
        float v = acc[m][n][q] + bias;
        v = v > 0.f ? v : 0.f;
        hid[(size_t)(gm0 + q) * DIM + gn] = f2bf(v);
      }
    }
  }
}

// ---- GEMM2: out = hid @ W2 + b2, f32 out [N_ABOVE][256] ----
__global__ __launch_bounds__(256, 2) void k_gemm2(
    const unsigned short* __restrict__ hid,   // [MPAD][256] bf16
    const unsigned short* __restrict__ w2t,   // [256][256] bf16 (W2 transposed)
    const float* __restrict__ b2,
    float* __restrict__ out)
{
  __shared__ __align__(16) unsigned short Alds[128 * 64];
  __shared__ __align__(16) unsigned short Blds[128 * 64];

  const int tid = threadIdx.x;
  const int w = tid >> 6, l = tid & 63;
  const int m0 = blockIdx.x * 128, n0 = blockIdx.y * 128;
  const int wm = w >> 1, wn = w & 1;
  const int srow = l >> 3, slot = l & 7;

  f32x4 acc[4][4] = {};

  for (int t = 0; t < 4; ++t) {
    __syncthreads();
#pragma unroll
    for (int i = 0; i < 4; ++i) {
      int row = w * 32 + i * 8 + srow;
      int c = slot ^ (row & 7);
      gload16(hid + (size_t)(m0 + row) * DIM + (t << 6) + (c << 3),
              Alds + (w * 32 + i * 8) * 64);
      gload16(w2t + (size_t)(n0 + row) * DIM + (t << 6) + (c << 3),
              Blds + (w * 32 + i * 8) * 64);
    }
    __syncthreads();

#pragma unroll
    for (int kk = 0; kk < 2; ++kk) {
      bf16x8 af[4], bfr[4];
#pragma unroll
      for (int m = 0; m < 4; ++m) {
        int row = wm * 64 + m * 16 + (l & 15);
        int c = (kk * 4 + (l >> 4)) ^ (row & 7);
        af[m] = *(const bf16x8*)(Alds + row * 64 + c * 8);
      }
#pragma unroll
      for (int n = 0; n < 4; ++n) {
        int row = wn * 64 + n * 16 + (l & 15);
        int c = (kk * 4 + (l >> 4)) ^ (row & 7);
        bfr[n] = *(const bf16x8*)(Blds + row * 64 + c * 8);
      }
#pragma unroll
      for (int m = 0; m < 4; ++m)
#pragma unroll
        for (int n = 0; n < 4; ++n)
          acc[m][n] = __builtin_amdgcn_mfma_f32_16x16x32_bf16(af[m], bfr[n], acc[m][n], 0, 0, 0);
    }
  }

#pragma unroll
  for (int n = 0; n < 4; ++n) {
    int gn = n0 + wn * 64 + n * 16 + (l & 15);
    float bias = b2[gn];
#pragma unroll
    for (int m = 0; m < 4; ++m) {
      int gm0 = m0 + wm * 64 + m * 16 + (l >> 4) * 4;
#pragma unroll
      for (int q = 0; q < 4; ++q) {
        int gm = gm0 + q;
        if (gm < N_ABOVE) out[(size_t)gm * DIM + gn] = acc[m][n][q] + bias;
      }
    }
  }
}

extern "C" void kernel_launch(void* const* d_in, const int* in_sizes, int n_in,
                              void* d_out, int out_size, void* d_ws, size_t ws_size,
                              hipStream_t stream) {
  const float* h    = (const float*)d_in[0];
  // d_in[1]: h_above (unused, only shape)
  const int*   idx  = (const int*)d_in[2];
  // d_in[3]: i (unused — implied by fixed fan-in bucketing)
  const int*   jarr = (const int*)d_in[4];
  const float* W1   = (const float*)d_in[5];
  const float* b1   = (const float*)d_in[6];
  const float* W2   = (const float*)d_in[7];
  const float* b2   = (const float*)d_in[8];
  float* out = (float*)d_out;

  char* ws = (char*)d_ws;
  size_t off = 0;
  auto alloc = [&](size_t bytes) -> void* {
    void* p = ws + off;
    off += bytes;
    off = (off + 511) & ~(size_t)511;
    return p;
  };
  int*            inv = (int*)alloc((size_t)N_ABOVE * 4);
  unsigned short* hbf = (unsigned short*)alloc((size_t)(N_DOWN + 1) * DIM * 2);
  unsigned short* w1t = (unsigned short*)alloc((size_t)DIM * K1 * 2);
  unsigned short* w2t = (unsigned short*)alloc((size_t)DIM * DIM * 2);
  unsigned short* hid = (unsigned short*)alloc((size_t)MPAD * DIM * 2);
  if (ws_size < off) return;  // workspace too small: fail loudly (output stays poisoned)

  k_prep_inv<<<dim3(391), dim3(256), 0, stream>>>(inv, hbf);
  k_scatter<<<dim3(196), dim3(256), 0, stream>>>(idx, inv);
  k_h2bf<<<dim3(12500), dim3(256), 0, stream>>>(h, hbf);
  k_transpose_bf<<<dim3(K1 / 64, DIM / 64), dim3(256), 0, stream>>>(W1, w1t, K1, DIM);
  k_transpose_bf<<<dim3(DIM / 64, DIM / 64), dim3(256), 0, stream>>>(W2, w2t, DIM, DIM);
  k_gemm1<<<dim3(MPAD / 128, 2), dim3(256), 0, stream>>>(hbf, w1t, b1, inv, jarr, hid);
  k_gemm2<<<dim3(MPAD / 128, 2), dim3(256), 0, stream>>>(hid, w2t, b2, out);
}